// Round 1
// baseline (12043.781 us; speedup 1.0000x reference)
//
#include <hip/hip_runtime.h>
#include <hip/hip_fp16.h>
#include <stdint.h>

typedef _Float16 h16;
typedef h16  half8  __attribute__((ext_vector_type(8)));
typedef h16  half4v __attribute__((ext_vector_type(4)));
typedef float f32x4 __attribute__((ext_vector_type(4)));

#define NB 64
#define NT 512
#define ND 256
#define NH 1024

#define AT_LD(p)   __hip_atomic_load((p),      __ATOMIC_RELAXED, __HIP_MEMORY_SCOPE_AGENT)
#define AT_ST(p,v) __hip_atomic_store((p),(v), __ATOMIC_RELAXED, __HIP_MEMORY_SCOPE_AGENT)

// ---------------- prep: x fp32 -> fp16 ----------------
__global__ void k_cvt_x(const float* __restrict__ x, h16* __restrict__ xo, int n4){
  int i = blockIdx.x*blockDim.x + threadIdx.x;
  if (i >= n4) return;
  const float4 v = ((const float4*)x)[i];
  half4v o; o[0]=(h16)v.x; o[1]=(h16)v.y; o[2]=(h16)v.z; o[3]=(h16)v.w;
  ((half4v*)xo)[i] = o;
}

// ---------------- prep: pack W [4096,K] fp32 -> fp16 MFMA-B-fragment order ----
// unit (nt, ks): 64 lanes x 8 halves ; value = W[nt*16 + (l&15)][ks*32 + (l>>4)*8 + j]
__global__ void k_pack_w(const float* __restrict__ W, h16* __restrict__ P, int K){
  int tid = blockIdx.x*blockDim.x + threadIdx.x;
  int KS = K >> 5;
  int total = 256*KS*64;
  if (tid >= total) return;
  int l  = tid & 63;
  int ks = (tid >> 6) % KS;
  int nt = tid / (KS*64);
  const float* src = W + (size_t)(nt*16 + (l&15))*K + ks*32 + ((l>>4)<<3);
  float4 v0 = ((const float4*)src)[0];
  float4 v1 = ((const float4*)src)[1];
  half8 o;
  o[0]=(h16)v0.x; o[1]=(h16)v0.y; o[2]=(h16)v0.z; o[3]=(h16)v0.w;
  o[4]=(h16)v1.x; o[5]=(h16)v1.y; o[6]=(h16)v1.z; o[7]=(h16)v1.w;
  *(half8*)(P + (size_t)tid*8) = o;
}

// ---------------- persistent 2-layer LSTM ----------------
// 256 WGs x 256 threads. wid>>7 = layer. Within layer: xcd=i2&7, slot=i2>>3,
// mh=slot&1 (batch half, rows 32*mh..+32), cg = xcd*8 + (slot>>1) (16 h-cols).
// Iteration k: layer0 does step t=k (k<512), layer1 does step t=k-1 (k>=1).
// h ping-pong: state after iter k lives at parity k&1. All h traffic via
// agent-scope relaxed atomics (bypasses non-coherent per-XCD L2s).
__launch_bounds__(256, 1)
__global__ void k_lstm(const h16* __restrict__ xf,
                       const h16* __restrict__ w0p, const h16* __restrict__ wh0p,
                       const h16* __restrict__ w1p, const h16* __restrict__ wh1p,
                       const float* __restrict__ b0, const float* __restrict__ b1,
                       const float* __restrict__ wfc, const float* __restrict__ bfc,
                       h16* __restrict__ h0b, h16* __restrict__ h1b,
                       int* __restrict__ flags, float* __restrict__ out)
{
  __shared__ h16  a_lds[2][2][8][64][8];   // [buf][mtile][ks][lane][8]  32 KB
  __shared__ float gl[4][2][16][16];       // [gate][mtile][row][col]     8 KB

  const int tid   = threadIdx.x;
  const int lane  = tid & 63;
  const int wv    = tid >> 6;          // wave id == gate id (i,f,g,o)
  const int wid   = blockIdx.x;
  const int layer = wid >> 7;
  const int i2    = wid & 127;
  const int xcd   = i2 & 7;
  const int slot  = i2 >> 3;
  const int mh    = slot & 1;
  const int cg    = xcd*8 + (slot>>1); // 0..63

  // elementwise mapping: 2 adjacent cols per thread
  const int erow  = tid >> 3;          // 0..31 (local batch row)
  const int ecol  = (tid & 7) << 1;    // 0,2,..,14
  const int gcol0 = cg*16 + ecol;      // global h column (even)

  float bia[8];
  {
    const float* bb = layer ? b1 : b0;
    bia[0]=bb[0*NH+gcol0]; bia[1]=bb[0*NH+gcol0+1];
    bia[2]=bb[1*NH+gcol0]; bia[3]=bb[1*NH+gcol0+1];
    bia[4]=bb[2*NH+gcol0]; bia[5]=bb[2*NH+gcol0+1];
    bia[6]=bb[3*NH+gcol0]; bia[7]=bb[3*NH+gcol0+1];
  }
  float c0 = 0.f, c1 = 0.f;
  h16* myh = layer ? h1b : h0b;

  // ---- init: zero my h block in both parities, then barrier stamp 1 ----
  for (int p = 0; p < 2; ++p) {
    uint32_t* dst = (uint32_t*)(myh + (size_t)p*NB*NH + (size_t)(32*mh + erow)*NH + gcol0);
    AT_ST(dst, 0u);
  }
  asm volatile("s_waitcnt vmcnt(0)" ::: "memory");
  __syncthreads();
  if (tid == 0) AT_ST(&flags[wid], 1);
  {
    int guard = 0;
    while (AT_LD((const int*)&flags[tid]) < 1) {
      __builtin_amdgcn_s_sleep(4);
      if (++guard > (1<<20)) break;
    }
  }
  __syncthreads();

  // ---- main loop: 513 iterations ----
  for (int k = 0; k <= NT; ++k) {
    const bool active = (layer == 0) ? (k < NT) : (k >= 1);
    if (active) {
      f32x4 acc0 = {0.f,0.f,0.f,0.f}, acc1 = {0.f,0.f,0.f,0.f};

      const h16* sA[2]; int sRS[2]; const h16* sW[2]; int sNC[2]; bool sAt[2];
      const size_t pprev = (size_t)((k+1)&1)*NB*NH;   // parity (k-1)&1
      if (layer == 0) {
        sA[0] = xf + (size_t)(32*mh)*NT*ND + (size_t)k*ND;
        sRS[0]=NT*ND; sW[0]=w0p;  sNC[0]=1; sAt[0]=false;
        sA[1] = h0b + pprev + (size_t)(32*mh)*NH;
        sRS[1]=NH;    sW[1]=wh0p; sNC[1]=4; sAt[1]=true;
      } else {
        sA[0] = h0b + pprev + (size_t)(32*mh)*NH;     // y0[t=k-1]
        sRS[0]=NH;    sW[0]=w1p;  sNC[0]=4; sAt[0]=true;
        sA[1] = h1b + pprev + (size_t)(32*mh)*NH;
        sRS[1]=NH;    sW[1]=wh1p; sNC[1]=4; sAt[1]=true;
      }
      const int NCtot = sNC[0] + sNC[1];

      auto stage = [&](int ci){
        int s = (ci >= sNC[0]) ? 1 : 0;
        int c = ci - (s ? sNC[0] : 0);
        const h16* base = sA[s] + (c<<8);
        const int RS = sRS[s];
        const bool at = sAt[s];
        const int bufi = ci & 1;
        #pragma unroll
        for (int i = 0; i < 4; ++i) {
          int sl  = tid + (i<<8);        // slot 0..1023
          int m   = sl >> 9;
          int rem = sl & 511;
          int ks  = rem >> 6;
          int ln  = rem & 63;
          int row = (m<<4) + (ln & 15);
          int kl  = (ks<<5) + ((ln>>4)<<3);
          const unsigned long long* gp =
            (const unsigned long long*)(base + (size_t)row*RS + kl);
          unsigned long long u0, u1;
          if (at) { u0 = AT_LD((unsigned long long*)gp);
                    u1 = AT_LD((unsigned long long*)(gp+1)); }
          else    { u0 = gp[0]; u1 = gp[1]; }
          unsigned long long* lp = (unsigned long long*)(&a_lds[bufi][m][ks][ln][0]);
          lp[0] = u0; lp[1] = u1;
        }
      };
      auto mma = [&](int ci){
        int s = (ci >= sNC[0]) ? 1 : 0;
        int c = ci - (s ? sNC[0] : 0);
        int KS = sNC[s] << 3;
        const h16* wb = sW[s] + (((size_t)(64*wv + cg)*KS + (size_t)(c<<3)) << 9);
        const int bufi = ci & 1;
        #pragma unroll
        for (int ks = 0; ks < 8; ++ks) {
          half8 a0 = *(const half8*)(&a_lds[bufi][0][ks][lane][0]);
          half8 a1 = *(const half8*)(&a_lds[bufi][1][ks][lane][0]);
          half8 bw = *(const half8*)(wb + ((size_t)ks<<9) + (lane<<3));
          acc0 = __builtin_amdgcn_mfma_f32_16x16x32_f16(a0, bw, acc0, 0,0,0);
          acc1 = __builtin_amdgcn_mfma_f32_16x16x32_f16(a1, bw, acc1, 0,0,0);
        }
      };

      stage(0);
      __syncthreads();
      for (int ci = 0; ci < NCtot; ++ci) {
        if (ci + 1 < NCtot) stage(ci+1);
        mma(ci);
        __syncthreads();
      }

      // gates -> LDS (C layout: col=lane&15, row=(lane>>4)*4+reg)
      #pragma unroll
      for (int r = 0; r < 4; ++r) {
        gl[wv][0][((lane>>4)<<2)+r][lane&15] = acc0[r];
        gl[wv][1][((lane>>4)<<2)+r][lane&15] = acc1[r];
      }
      __syncthreads();

      // elementwise: 2 elems per thread
      const int m  = erow >> 4;
      const int rr = erow & 15;
      float xi0 = gl[0][m][rr][ecol]   + bia[0];
      float xi1 = gl[0][m][rr][ecol+1] + bia[1];
      float xf0 = gl[1][m][rr][ecol]   + bia[2];
      float xf1 = gl[1][m][rr][ecol+1] + bia[3];
      float xg0 = gl[2][m][rr][ecol]   + bia[4];
      float xg1 = gl[2][m][rr][ecol+1] + bia[5];
      float xo0 = gl[3][m][rr][ecol]   + bia[6];
      float xo1 = gl[3][m][rr][ecol+1] + bia[7];
      float ii0 = 1.f/(1.f+__expf(-xi0));
      float ii1 = 1.f/(1.f+__expf(-xi1));
      float ff0 = 1.f/(1.f+__expf(-xf0));
      float ff1 = 1.f/(1.f+__expf(-xf1));
      float tg0 = 1.f - 2.f/(__expf(2.f*xg0)+1.f);
      float tg1 = 1.f - 2.f/(__expf(2.f*xg1)+1.f);
      float oo0 = 1.f/(1.f+__expf(-xo0));
      float oo1 = 1.f/(1.f+__expf(-xo1));
      c0 = ff0*c0 + ii0*tg0;
      c1 = ff1*c1 + ii1*tg1;
      float hv0 = oo0*(1.f - 2.f/(__expf(2.f*c0)+1.f));
      float hv1 = oo1*(1.f - 2.f/(__expf(2.f*c1)+1.f));
      union { h16 h[2]; uint32_t u; } pk;
      pk.h[0] = (h16)hv0; pk.h[1] = (h16)hv1;
      uint32_t* dst = (uint32_t*)(myh + (size_t)(k&1)*NB*NH + (size_t)(32*mh + erow)*NH + gcol0);
      AT_ST(dst, pk.u);
    }

    // ---- device-wide barrier (stamp k+2) ----
    asm volatile("s_waitcnt vmcnt(0)" ::: "memory");
    __syncthreads();
    if (tid == 0) AT_ST(&flags[wid], k+2);
    {
      int guard = 0;
      while (AT_LD((const int*)&flags[tid]) < k+2) {
        __builtin_amdgcn_s_sleep(4);
        if (++guard > (1<<20)) break;
      }
    }
    __syncthreads();
  }

  // ---- final: out[b] = h1[b,:] . wfc + bfc  (h1 parity 0 after iter 512) ----
  if (wid != 0) return;
  {
    const int b = tid >> 2, q = tid & 3;
    const unsigned long long* hp =
      (const unsigned long long*)(h1b + (size_t)b*NH + (size_t)q*256);
    const float* wr = wfc + q*256;
    float s = 0.f;
    #pragma unroll 4
    for (int u = 0; u < 64; ++u) {
      unsigned long long v = AT_LD((unsigned long long*)(hp + u));
      h16 hh[4]; __builtin_memcpy(hh, &v, 8);
      s += (float)hh[0]*wr[4*u] + (float)hh[1]*wr[4*u+1]
         + (float)hh[2]*wr[4*u+2] + (float)hh[3]*wr[4*u+3];
    }
    ((float*)gl)[tid] = s;
    __syncthreads();
    if (tid < 64) {
      const float* g0 = (const float*)gl;
      out[tid] = g0[4*tid] + g0[4*tid+1] + g0[4*tid+2] + g0[4*tid+3] + bfc[0];
    }
  }
}

extern "C" void kernel_launch(void* const* d_in, const int* in_sizes, int n_in,
                              void* d_out, int out_size, void* d_ws, size_t ws_size,
                              hipStream_t stream) {
  const float* x    = (const float*)d_in[0];
  const float* Wih0 = (const float*)d_in[1];
  const float* Whh0 = (const float*)d_in[2];
  const float* b0   = (const float*)d_in[3];
  const float* Wih1 = (const float*)d_in[4];
  const float* Whh1 = (const float*)d_in[5];
  const float* b1   = (const float*)d_in[6];
  const float* Wfc  = (const float*)d_in[7];
  const float* bfc  = (const float*)d_in[8];

  char* ws = (char*)d_ws;
  size_t off = 0;
  auto alloc = [&](size_t bytes)->void* {
    void* p = ws + off; off += (bytes + 255) & ~(size_t)255; return p;
  };
  h16* xf   = (h16*)alloc((size_t)NB*NT*ND*2);
  h16* w0p  = (h16*)alloc((size_t)4096*ND*2);
  h16* wh0p = (h16*)alloc((size_t)4096*NH*2);
  h16* w1p  = (h16*)alloc((size_t)4096*NH*2);
  h16* wh1p = (h16*)alloc((size_t)4096*NH*2);
  h16* h0b  = (h16*)alloc((size_t)2*NB*NH*2);
  h16* h1b  = (h16*)alloc((size_t)2*NB*NH*2);
  int* flags= (int*)alloc(256*sizeof(int));

  {
    int n4 = NB*NT*ND/4;
    k_cvt_x<<<(n4+255)/256, 256, 0, stream>>>(x, xf, n4);
  }
  k_pack_w<<<(256*(ND/32)*64 + 255)/256, 256, 0, stream>>>(Wih0, w0p, ND);
  k_pack_w<<<(256*(NH/32)*64 + 255)/256, 256, 0, stream>>>(Whh0, wh0p, NH);
  k_pack_w<<<(256*(NH/32)*64 + 255)/256, 256, 0, stream>>>(Wih1, w1p, NH);
  k_pack_w<<<(256*(NH/32)*64 + 255)/256, 256, 0, stream>>>(Whh1, wh1p, NH);

  k_lstm<<<256, 256, 0, stream>>>(xf, w0p, wh0p, w1p, wh1p,
                                  b0, b1, Wfc, bfc, h0b, h1b, flags,
                                  (float*)d_out);
}

// Round 2
// 8106.097 us; speedup vs baseline: 1.4858x; 1.4858x over previous
//
#include <hip/hip_runtime.h>
#include <hip/hip_fp16.h>
#include <stdint.h>

typedef _Float16 h16;
typedef h16  half8  __attribute__((ext_vector_type(8)));
typedef h16  half4v __attribute__((ext_vector_type(4)));
typedef float f32x4 __attribute__((ext_vector_type(4)));
typedef uint32_t u32x4 __attribute__((ext_vector_type(4)));

#define NB 64
#define NT 512
#define ND 256
#define NH 1024

#define AT_LD(p)   __hip_atomic_load((p),      __ATOMIC_RELAXED, __HIP_MEMORY_SCOPE_AGENT)
#define AT_ST(p,v) __hip_atomic_store((p),(v), __ATOMIC_RELAXED, __HIP_MEMORY_SCOPE_AGENT)

// Coherent (L1+L2-bypass) 16B load / 4B store: reads/writes at the IF$
// coherence point, valid cross-XCD after a flag barrier. Plain instruction ->
// back-to-back issue, tracked manually via counted vmcnt.
__device__ __forceinline__ u32x4 cload16(const void* p){
  u32x4 d;
  asm volatile("global_load_dwordx4 %0, %1, off sc0 sc1" : "=v"(d) : "v"(p) : "memory");
  return d;
}
__device__ __forceinline__ void cstore4(void* p, uint32_t v){
  asm volatile("global_store_dword %0, %1, off sc0 sc1" :: "v"(p), "v"(v) : "memory");
}
#define VMW(n) asm volatile("s_waitcnt vmcnt(" #n ")" ::: "memory")

#define WRC(A,c) do{ \
  *(u32x4*)(shb + (c)*16384 + ldsb_[0]) = A[(c)*4+0]; \
  *(u32x4*)(shb + (c)*16384 + ldsb_[1]) = A[(c)*4+1]; \
  *(u32x4*)(shb + (c)*16384 + ldsb_[2]) = A[(c)*4+2]; \
  *(u32x4*)(shb + (c)*16384 + ldsb_[3]) = A[(c)*4+3]; \
}while(0)

// ---------------- prep: x fp32 -> fp16 ----------------
__global__ void k_cvt_x(const float* __restrict__ x, h16* __restrict__ xo, int n4){
  int i = blockIdx.x*blockDim.x + threadIdx.x;
  if (i >= n4) return;
  const float4 v = ((const float4*)x)[i];
  half4v o; o[0]=(h16)v.x; o[1]=(h16)v.y; o[2]=(h16)v.z; o[3]=(h16)v.w;
  ((half4v*)xo)[i] = o;
}

// ---------------- prep: pack W [4096,K] fp32 -> fp16 MFMA-B-fragment order ----
__global__ void k_pack_w(const float* __restrict__ W, h16* __restrict__ P, int K){
  int tid = blockIdx.x*blockDim.x + threadIdx.x;
  int KS = K >> 5;
  int total = 256*KS*64;
  if (tid >= total) return;
  int l  = tid & 63;
  int ks = (tid >> 6) % KS;
  int nt = tid / (KS*64);
  const float* src = W + (size_t)(nt*16 + (l&15))*K + ks*32 + ((l>>4)<<3);
  float4 v0 = ((const float4*)src)[0];
  float4 v1 = ((const float4*)src)[1];
  half8 o;
  o[0]=(h16)v0.x; o[1]=(h16)v0.y; o[2]=(h16)v0.z; o[3]=(h16)v0.w;
  o[4]=(h16)v1.x; o[5]=(h16)v1.y; o[6]=(h16)v1.z; o[7]=(h16)v1.w;
  *(half8*)(P + (size_t)tid*8) = o;
}

// ---------------- persistent 2-layer LSTM ----------------
// 256 WGs x 256 threads, 1 WG/CU. wid>>7 = layer. xcd=i2&7 aligns with the
// round-robin WG->XCD dispatch so each XCD's weight slice (~3.4 MB) is
// L2-resident. Per iteration: issue ALL A-loads (coherent 16B asm), counted
// vmcnt -> LDS writes, one sync, full MFMA sweep, gates, h-store, flag barrier.
__launch_bounds__(256, 1)
__global__ void k_lstm(const h16* __restrict__ xf,
                       const h16* __restrict__ w0p, const h16* __restrict__ wh0p,
                       const h16* __restrict__ w1p, const h16* __restrict__ wh1p,
                       const float* __restrict__ b0, const float* __restrict__ b1,
                       const float* __restrict__ wfc, const float* __restrict__ bfc,
                       h16* __restrict__ h0b, h16* __restrict__ h1b,
                       int* __restrict__ flags, float* __restrict__ out)
{
  extern __shared__ char shb[];                 // [0,131072) A-panel, [131072,+8K) gates
  float* glf = (float*)(shb + 131072);          // [4][2][16][16] f32

  const int tid   = threadIdx.x;
  const int lane  = tid & 63;
  const int wv    = tid >> 6;          // wave id == gate id (i,f,g,o)
  const int wid   = blockIdx.x;
  const int layer = wid >> 7;
  const int i2    = wid & 127;
  const int xcd   = i2 & 7;
  const int slot  = i2 >> 3;
  const int mh    = slot & 1;
  const int cg    = xcd*8 + (slot>>1); // 0..63

  const int erow  = tid >> 3;          // 0..31 (local batch row)
  const int ecol  = (tid & 7) << 1;
  const int gcol0 = cg*16 + ecol;

  // per-thread staging geometry (iteration-invariant)
  int row_[4], kl_[4], ldsb_[4];
  #pragma unroll
  for (int i = 0; i < 4; ++i) {
    int sl = tid + (i<<8), m = sl>>9, rem = sl&511, ks = rem>>6, ln = rem&63;
    row_[i]  = (m<<4) + (ln&15);
    kl_[i]   = (ks<<5) + ((ln>>4)<<3);
    ldsb_[i] = ((((m<<3)+ks)<<6) + ln) << 4;
  }

  float bia[8];
  {
    const float* bb = layer ? b1 : b0;
    bia[0]=bb[0*NH+gcol0]; bia[1]=bb[0*NH+gcol0+1];
    bia[2]=bb[1*NH+gcol0]; bia[3]=bb[1*NH+gcol0+1];
    bia[4]=bb[2*NH+gcol0]; bia[5]=bb[2*NH+gcol0+1];
    bia[6]=bb[3*NH+gcol0]; bia[7]=bb[3*NH+gcol0+1];
  }
  float c0 = 0.f, c1 = 0.f;
  h16* myh = layer ? h1b : h0b;

  // ---- init: zero my h block in both parities, then barrier stamp 1 ----
  for (int p = 0; p < 2; ++p) {
    uint32_t* dst = (uint32_t*)(myh + (size_t)p*NB*NH + (size_t)(32*mh + erow)*NH + gcol0);
    AT_ST(dst, 0u);
  }
  asm volatile("s_waitcnt vmcnt(0)" ::: "memory");
  __syncthreads();
  if (tid == 0) AT_ST(&flags[wid], 1);
  {
    int guard = 0;
    while (AT_LD((const int*)&flags[tid]) < 1) {
      __builtin_amdgcn_s_sleep(1);
      if (++guard > (1<<22)) break;
    }
  }
  __syncthreads();

  // ---- main loop: 513 iterations ----
  for (int k = 0; k <= NT; ++k) {
    const bool active = (layer == 0) ? (k < NT) : (k >= 1);
    if (active) {
      const size_t poff = (size_t)((k+1)&1)*NB*NH;         // parity (k-1)&1
      const h16* s0 = h0b + poff + (size_t)(32*mh)*NH;     // h0[t-1] rows
      f32x4 acm[2][2] = {{{0.f,0.f,0.f,0.f},{0.f,0.f,0.f,0.f}},
                         {{0.f,0.f,0.f,0.f},{0.f,0.f,0.f,0.f}}};

      if (layer == 0) {
        // ---- stage: chunk0 = x[t], chunks1-4 = h0[t-1] (20 loads) ----
        u32x4 st[20];
        const h16* xb = xf + (size_t)(32*mh)*NT*ND + (size_t)k*ND;
        #pragma unroll
        for (int i = 0; i < 4; ++i)
          st[i] = cload16(xb + (size_t)row_[i]*NT*ND + kl_[i]);
        #pragma unroll
        for (int c = 0; c < 4; ++c)
          #pragma unroll
          for (int i = 0; i < 4; ++i)
            st[4 + c*4 + i] = cload16(s0 + (size_t)row_[i]*NH + (c<<8) + kl_[i]);
        VMW(16); WRC(st,0);
        VMW(12); WRC(st,1);
        VMW(8);  WRC(st,2);
        VMW(4);  WRC(st,3);
        VMW(0);  WRC(st,4);
        __syncthreads();

        // ---- MFMA sweep ----
        const h16* wX = w0p  + ((size_t)((wv<<6)+cg) << 12);   // *8*512
        const h16* wH = wh0p + ((size_t)((wv<<6)+cg) << 14);   // *32*512
        #pragma unroll
        for (int ks2 = 0; ks2 < 8; ++ks2) {
          half8 a0 = *(const half8*)(shb + (((ks2<<6)+lane)<<4));
          half8 a1 = *(const half8*)(shb + (((512)+(ks2<<6)+lane)<<4));
          half8 bw = *(const half8*)(wX + (ks2<<9) + (lane<<3));
          const int p = ks2&1;
          acm[0][p] = __builtin_amdgcn_mfma_f32_16x16x32_f16(a0,bw,acm[0][p],0,0,0);
          acm[1][p] = __builtin_amdgcn_mfma_f32_16x16x32_f16(a1,bw,acm[1][p],0,0,0);
        }
        #pragma unroll
        for (int c = 0; c < 4; ++c)
          #pragma unroll
          for (int ks2 = 0; ks2 < 8; ++ks2) {
            half8 a0 = *(const half8*)(shb + (1+c)*16384 + (((ks2<<6)+lane)<<4));
            half8 a1 = *(const half8*)(shb + (1+c)*16384 + (((512)+(ks2<<6)+lane)<<4));
            half8 bw = *(const half8*)(wH + (((c<<3)+ks2)<<9) + (lane<<3));
            const int p = ks2&1;
            acm[0][p] = __builtin_amdgcn_mfma_f32_16x16x32_f16(a0,bw,acm[0][p],0,0,0);
            acm[1][p] = __builtin_amdgcn_mfma_f32_16x16x32_f16(a1,bw,acm[1][p],0,0,0);
          }
      } else {
        // ---- stage: chunks0-3 = h0[t-1], chunks4-7 = h1[t-1] (32 loads) ----
        u32x4 st[32];
        const h16* s1 = h1b + poff + (size_t)(32*mh)*NH;
        #pragma unroll
        for (int c = 0; c < 4; ++c)
          #pragma unroll
          for (int i = 0; i < 4; ++i)
            st[c*4 + i] = cload16(s0 + (size_t)row_[i]*NH + (c<<8) + kl_[i]);
        #pragma unroll
        for (int c = 0; c < 4; ++c)
          #pragma unroll
          for (int i = 0; i < 4; ++i)
            st[16 + c*4 + i] = cload16(s1 + (size_t)row_[i]*NH + (c<<8) + kl_[i]);
        VMW(28); WRC(st,0);
        VMW(24); WRC(st,1);
        VMW(20); WRC(st,2);
        VMW(16); WRC(st,3);
        VMW(12); WRC(st,4);
        VMW(8);  WRC(st,5);
        VMW(4);  WRC(st,6);
        VMW(0);  WRC(st,7);
        __syncthreads();

        // ---- MFMA sweep ----
        const h16* wA = w1p  + ((size_t)((wv<<6)+cg) << 14);   // *32*512
        const h16* wB = wh1p + ((size_t)((wv<<6)+cg) << 14);
        #pragma unroll
        for (int c = 0; c < 4; ++c)
          #pragma unroll
          for (int ks2 = 0; ks2 < 8; ++ks2) {
            half8 a0 = *(const half8*)(shb + c*16384 + (((ks2<<6)+lane)<<4));
            half8 a1 = *(const half8*)(shb + c*16384 + (((512)+(ks2<<6)+lane)<<4));
            half8 bw = *(const half8*)(wA + (((c<<3)+ks2)<<9) + (lane<<3));
            const int p = ks2&1;
            acm[0][p] = __builtin_amdgcn_mfma_f32_16x16x32_f16(a0,bw,acm[0][p],0,0,0);
            acm[1][p] = __builtin_amdgcn_mfma_f32_16x16x32_f16(a1,bw,acm[1][p],0,0,0);
          }
        #pragma unroll
        for (int c = 0; c < 4; ++c)
          #pragma unroll
          for (int ks2 = 0; ks2 < 8; ++ks2) {
            half8 a0 = *(const half8*)(shb + (4+c)*16384 + (((ks2<<6)+lane)<<4));
            half8 a1 = *(const half8*)(shb + (4+c)*16384 + (((512)+(ks2<<6)+lane)<<4));
            half8 bw = *(const half8*)(wB + (((c<<3)+ks2)<<9) + (lane<<3));
            const int p = ks2&1;
            acm[0][p] = __builtin_amdgcn_mfma_f32_16x16x32_f16(a0,bw,acm[0][p],0,0,0);
            acm[1][p] = __builtin_amdgcn_mfma_f32_16x16x32_f16(a1,bw,acm[1][p],0,0,0);
          }
      }

      // ---- gates -> LDS (C layout: col=lane&15, row=(lane>>4)*4+reg) ----
      f32x4 A0 = acm[0][0] + acm[0][1];
      f32x4 A1 = acm[1][0] + acm[1][1];
      #pragma unroll
      for (int r = 0; r < 4; ++r) {
        glf[((((wv<<1)+0)<<4) + ((lane>>4)<<2)+r)*16 + (lane&15)] = A0[r];
        glf[((((wv<<1)+1)<<4) + ((lane>>4)<<2)+r)*16 + (lane&15)] = A1[r];
      }
      __syncthreads();

      // ---- elementwise: 2 elems per thread ----
      const int m  = erow >> 4;
      const int rr = erow & 15;
      float xi0 = glf[(((0*2+m)<<4)+rr)*16+ecol]   + bia[0];
      float xi1 = glf[(((0*2+m)<<4)+rr)*16+ecol+1] + bia[1];
      float xf0 = glf[(((1*2+m)<<4)+rr)*16+ecol]   + bia[2];
      float xf1 = glf[(((1*2+m)<<4)+rr)*16+ecol+1] + bia[3];
      float xg0 = glf[(((2*2+m)<<4)+rr)*16+ecol]   + bia[4];
      float xg1 = glf[(((2*2+m)<<4)+rr)*16+ecol+1] + bia[5];
      float xo0 = glf[(((3*2+m)<<4)+rr)*16+ecol]   + bia[6];
      float xo1 = glf[(((3*2+m)<<4)+rr)*16+ecol+1] + bia[7];
      float ii0 = 1.f/(1.f+__expf(-xi0));
      float ii1 = 1.f/(1.f+__expf(-xi1));
      float ff0 = 1.f/(1.f+__expf(-xf0));
      float ff1 = 1.f/(1.f+__expf(-xf1));
      float tg0 = 1.f - 2.f/(__expf(2.f*xg0)+1.f);
      float tg1 = 1.f - 2.f/(__expf(2.f*xg1)+1.f);
      float oo0 = 1.f/(1.f+__expf(-xo0));
      float oo1 = 1.f/(1.f+__expf(-xo1));
      c0 = ff0*c0 + ii0*tg0;
      c1 = ff1*c1 + ii1*tg1;
      float hv0 = oo0*(1.f - 2.f/(__expf(2.f*c0)+1.f));
      float hv1 = oo1*(1.f - 2.f/(__expf(2.f*c1)+1.f));
      union { h16 h[2]; uint32_t u; } pk;
      pk.h[0] = (h16)hv0; pk.h[1] = (h16)hv1;
      cstore4(myh + (size_t)(k&1)*NB*NH + (size_t)(32*mh + erow)*NH + gcol0, pk.u);
    }

    // ---- device-wide barrier (stamp k+2) ----
    asm volatile("s_waitcnt vmcnt(0)" ::: "memory");
    __syncthreads();
    if (tid == 0) AT_ST(&flags[wid], k+2);
    {
      int guard = 0;
      while (AT_LD((const int*)&flags[tid]) < k+2) {
        __builtin_amdgcn_s_sleep(1);
        if (++guard > (1<<22)) break;
      }
    }
    __syncthreads();
  }

  // ---- final: out[b] = h1[b,:] . wfc + bfc  (h1 parity 0 after iter 512) ----
  if (wid != 0) return;
  {
    const int b = tid >> 2, q = tid & 3;
    const unsigned long long* hp =
      (const unsigned long long*)(h1b + (size_t)b*NH + (size_t)q*256);
    const float* wr = wfc + q*256;
    float s = 0.f;
    #pragma unroll 4
    for (int u = 0; u < 64; ++u) {
      unsigned long long v = AT_LD((unsigned long long*)(hp + u));
      h16 hh[4]; __builtin_memcpy(hh, &v, 8);
      s += (float)hh[0]*wr[4*u] + (float)hh[1]*wr[4*u+1]
         + (float)hh[2]*wr[4*u+2] + (float)hh[3]*wr[4*u+3];
    }
    glf[tid] = s;
    __syncthreads();
    if (tid < 64) {
      out[tid] = glf[4*tid] + glf[4*tid+1] + glf[4*tid+2] + glf[4*tid+3] + bfc[0];
    }
  }
}

extern "C" void kernel_launch(void* const* d_in, const int* in_sizes, int n_in,
                              void* d_out, int out_size, void* d_ws, size_t ws_size,
                              hipStream_t stream) {
  const float* x    = (const float*)d_in[0];
  const float* Wih0 = (const float*)d_in[1];
  const float* Whh0 = (const float*)d_in[2];
  const float* b0   = (const float*)d_in[3];
  const float* Wih1 = (const float*)d_in[4];
  const float* Whh1 = (const float*)d_in[5];
  const float* b1   = (const float*)d_in[6];
  const float* Wfc  = (const float*)d_in[7];
  const float* bfc  = (const float*)d_in[8];

  char* ws = (char*)d_ws;
  size_t off = 0;
  auto alloc = [&](size_t bytes)->void* {
    void* p = ws + off; off += (bytes + 255) & ~(size_t)255; return p;
  };
  h16* xf   = (h16*)alloc((size_t)NB*NT*ND*2);
  h16* w0p  = (h16*)alloc((size_t)4096*ND*2);
  h16* wh0p = (h16*)alloc((size_t)4096*NH*2);
  h16* w1p  = (h16*)alloc((size_t)4096*NH*2);
  h16* wh1p = (h16*)alloc((size_t)4096*NH*2);
  h16* h0b  = (h16*)alloc((size_t)2*NB*NH*2);
  h16* h1b  = (h16*)alloc((size_t)2*NB*NH*2);
  int* flags= (int*)alloc(256*sizeof(int));

  {
    int n4 = NB*NT*ND/4;
    k_cvt_x<<<(n4+255)/256, 256, 0, stream>>>(x, xf, n4);
  }
  k_pack_w<<<(256*(ND/32)*64 + 255)/256, 256, 0, stream>>>(Wih0, w0p, ND);
  k_pack_w<<<(256*(NH/32)*64 + 255)/256, 256, 0, stream>>>(Whh0, wh0p, NH);
  k_pack_w<<<(256*(NH/32)*64 + 255)/256, 256, 0, stream>>>(Wih1, w1p, NH);
  k_pack_w<<<(256*(NH/32)*64 + 255)/256, 256, 0, stream>>>(Whh1, wh1p, NH);

  (void)hipFuncSetAttribute((const void*)k_lstm,
                            hipFuncAttributeMaxDynamicSharedMemorySize, 139264);
  k_lstm<<<256, 256, 139264, stream>>>(xf, w0p, wh0p, w1p, wh1p,
                                       b0, b1, Wfc, bfc, h0b, h1b, flags,
                                       (float*)d_out);
}

// Round 4
// 6137.981 us; speedup vs baseline: 1.9622x; 1.3206x over previous
//
#include <hip/hip_runtime.h>
#include <hip/hip_fp16.h>
#include <stdint.h>

typedef _Float16 h16;
typedef h16  half8  __attribute__((ext_vector_type(8)));
typedef float f32x4 __attribute__((ext_vector_type(4)));
typedef uint32_t u32x4 __attribute__((ext_vector_type(4)));

#define NB 64
#define NT 512
#define ND 256
#define NH 1024
#define RING 64   // h0 ring depth (power of 2)

#define AT_LD(p)   __hip_atomic_load((p),      __ATOMIC_RELAXED, __HIP_MEMORY_SCOPE_AGENT)
#define AT_ST(p,v) __hip_atomic_store((p),(v), __ATOMIC_RELAXED, __HIP_MEMORY_SCOPE_AGENT)

// Coherent (L1/L2-bypass) 16B load / 4B store at the IF$ coherence point.
__device__ __forceinline__ u32x4 cload16(const void* p){
  u32x4 d;
  asm volatile("global_load_dwordx4 %0, %1, off sc0 sc1" : "=v"(d) : "v"(p) : "memory");
  return d;
}
__device__ __forceinline__ void cstore4(void* p, uint32_t v){
  asm volatile("global_store_dword %0, %1, off sc0 sc1" :: "v"(p), "v"(v) : "memory");
}
#define VMW0() asm volatile("s_waitcnt vmcnt(0)" ::: "memory")

// ---------------- prep: pack W [4096,K] fp32 -> fp16 MFMA-B-fragment order ----
__global__ void k_pack_w(const float* __restrict__ W, h16* __restrict__ P, int K){
  int tid = blockIdx.x*blockDim.x + threadIdx.x;
  int KS = K >> 5;
  int total = 256*KS*64;
  if (tid >= total) return;
  int l  = tid & 63;
  int ks = (tid >> 6) % KS;
  int nt = tid / (KS*64);
  const float* src = W + (size_t)(nt*16 + (l&15))*K + ks*32 + ((l>>4)<<3);
  float4 v0 = ((const float4*)src)[0];
  float4 v1 = ((const float4*)src)[1];
  half8 o;
  o[0]=(h16)v0.x; o[1]=(h16)v0.y; o[2]=(h16)v0.z; o[3]=(h16)v0.w;
  o[4]=(h16)v1.x; o[5]=(h16)v1.y; o[6]=(h16)v1.z; o[7]=(h16)v1.w;
  *(half8*)(P + (size_t)tid*8) = o;
}

// wave0 polls flags (lane l -> p0[l], optional p1[l]); others wait at barrier.
__device__ __forceinline__ void wgwaitP(const int* p0, int n0, const int* p1, int n1){
  if (threadIdx.x < 64) {
    int g = 0;
    for (;;) {
      bool ok = (AT_LD(p0 + threadIdx.x) >= n0);
      if (n1 >= 0) ok = ok && (AT_LD(p1 + threadIdx.x) >= n1);
      if (ok) break;
      __builtin_amdgcn_s_sleep(1);
      if (++g > (1<<22)) break;
    }
  }
  __syncthreads();
}

// ---------------- persistent decoupled 2-layer LSTM ----------------
// 256 WGs x 256 threads, 1 WG/CU. wid>>7 = layer; within layer: xcd=i2&7
// (weight slice L2-resident per XCD), mh = batch half, cg = 16-col group.
// Layer0 free-runs writing h0 into a 64-deep ring; layer1 trails via
// per-producer flags. Layer1 step s consumes h0[s] (staged in epilogue of
// step s-1 after fb0 >= s+1) and h1[s-1] (ping-pong).
__launch_bounds__(256, 1)
__global__ void k_lstm(const float* __restrict__ x,
                       const h16* __restrict__ w0p, const h16* __restrict__ wh0p,
                       const h16* __restrict__ w1p, const h16* __restrict__ wh1p,
                       const float* __restrict__ b0, const float* __restrict__ b1,
                       const float* __restrict__ wfc, const float* __restrict__ bfc,
                       h16* __restrict__ h0r, h16* __restrict__ h1r,
                       int* __restrict__ flags, float* __restrict__ out)
{
  extern __shared__ char shb[];                 // 8 chunks x 16KB A-panel, +8KB gates
  float* glf = (float*)(shb + 131072);

  const int tid   = threadIdx.x;
  const int lane  = tid & 63;
  const int wv    = tid >> 6;          // wave id == gate id (i,f,g,o)
  const int wid   = blockIdx.x;
  const int layer = wid >> 7;
  const int i2    = wid & 127;
  const int xcd   = i2 & 7;
  const int slot  = i2 >> 3;
  const int mh    = slot & 1;
  const int cg    = xcd*8 + (slot>>1); // 0..63

  const int erow  = tid >> 3;          // 0..31 local batch row
  const int ecol  = (tid & 7) << 1;
  const int gcol0 = cg*16 + ecol;

  const int fb0 = (mh<<6);             // f0 group base (this mh)
  const int fb1 = 128 + (mh<<6);       // f1 group base (this mh)
  const int fself = (layer ? fb1 : fb0) + cg;

  // per-thread staging geometry (iteration-invariant)
  int row_[4], kl_[4], ldsb_[4];
  #pragma unroll
  for (int i = 0; i < 4; ++i) {
    int sl = tid + (i<<8), m = sl>>9, rem = sl&511, ks = rem>>6, ln = rem&63;
    row_[i]  = (m<<4) + (ln&15);
    kl_[i]   = (ks<<5) + ((ln>>4)<<3);
    ldsb_[i] = ((((m<<3)+ks)<<6) + ln) << 4;
  }

  float bia[8];
  {
    const float* bb = layer ? b1 : b0;
    bia[0]=bb[0*NH+gcol0]; bia[1]=bb[0*NH+gcol0+1];
    bia[2]=bb[1*NH+gcol0]; bia[3]=bb[1*NH+gcol0+1];
    bia[4]=bb[2*NH+gcol0]; bia[5]=bb[2*NH+gcol0+1];
    bia[6]=bb[3*NH+gcol0]; bia[7]=bb[3*NH+gcol0+1];
  }
  float c0 = 0.f, c1 = 0.f;

  // ---- init: zero h0 ring slot RING-1 / h1 slot 1 (the t=-1 states), flag 0 ----
  {
    h16* z = layer ? (h1r + (size_t)1*NB*NH) : (h0r + (size_t)(RING-1)*NB*NH);
    cstore4(z + (size_t)(32*mh + erow)*NH + gcol0, 0u);
    VMW0();
    __syncthreads();
    if (tid == 0) AT_ST(&flags[fself], 0);
  }

  if (layer == 0) {
    // =================== LAYER 0 ===================
    for (int t = 0; t < NT; ++t) {
      f32x4 acm[2][2] = {{{0.f,0.f,0.f,0.f},{0.f,0.f,0.f,0.f}},
                         {{0.f,0.f,0.f,0.f},{0.f,0.f,0.f,0.f}}};

      // ---- x stage (plain f32 loads + cvt) into LDS chunk 0 ----
      {
        const float* xr = x + ((size_t)(32*mh)*NT + t)*ND;
        #pragma unroll
        for (int i = 0; i < 4; ++i) {
          const float* p = xr + (size_t)row_[i]*(NT*ND) + kl_[i];
          float4 v0 = ((const float4*)p)[0];
          float4 v1 = ((const float4*)p)[1];
          half8 o;
          o[0]=(h16)v0.x; o[1]=(h16)v0.y; o[2]=(h16)v0.z; o[3]=(h16)v0.w;
          o[4]=(h16)v1.x; o[5]=(h16)v1.y; o[6]=(h16)v1.z; o[7]=(h16)v1.w;
          *(half8*)(shb + ldsb_[i]) = o;
        }
      }

      // ---- wait peers (h0[t-1] ready); ring guard: slot t&63 holds h0[t-64],
      //      overwrite only after all layer1 peers staged it (fb1 >= t-RING+1) ----
      wgwaitP(flags + fb0, t, flags + fb1, (t >= RING) ? (t - RING + 1) : -1);

      // ---- issue h0[t-1] coherent loads; x-sweep overlaps their flight ----
      u32x4 st[16];
      {
        const h16* s0 = h0r + (size_t)((t+RING-1)&(RING-1))*NB*NH + (size_t)(32*mh)*NH;
        #pragma unroll
        for (int c = 0; c < 4; ++c)
          #pragma unroll
          for (int i = 0; i < 4; ++i)
            st[c*4+i] = cload16(s0 + (size_t)row_[i]*NH + (c<<8) + kl_[i]);
      }
      {
        const h16* wX = w0p + ((size_t)((wv<<6)+cg) << 12);
        #pragma unroll
        for (int ks2 = 0; ks2 < 8; ++ks2) {
          half8 a0 = *(const half8*)(shb + (((ks2<<6)+lane)<<4));
          half8 a1 = *(const half8*)(shb + ((512+(ks2<<6)+lane)<<4));
          half8 bw = *(const half8*)(wX + (ks2<<9) + (lane<<3));
          const int p = ks2&1;
          acm[0][p] = __builtin_amdgcn_mfma_f32_16x16x32_f16(a0,bw,acm[0][p],0,0,0);
          acm[1][p] = __builtin_amdgcn_mfma_f32_16x16x32_f16(a1,bw,acm[1][p],0,0,0);
        }
      }
      VMW0();
      #pragma unroll
      for (int c = 0; c < 4; ++c) {
        *(u32x4*)(shb + (1+c)*16384 + ldsb_[0]) = st[c*4+0];
        *(u32x4*)(shb + (1+c)*16384 + ldsb_[1]) = st[c*4+1];
        *(u32x4*)(shb + (1+c)*16384 + ldsb_[2]) = st[c*4+2];
        *(u32x4*)(shb + (1+c)*16384 + ldsb_[3]) = st[c*4+3];
      }
      __syncthreads();

      // ---- h-sweep (K=1024) ----
      {
        const h16* wH = wh0p + ((size_t)((wv<<6)+cg) << 14);
        #pragma unroll
        for (int c = 0; c < 4; ++c)
          #pragma unroll
          for (int ks2 = 0; ks2 < 8; ++ks2) {
            half8 a0 = *(const half8*)(shb + (1+c)*16384 + (((ks2<<6)+lane)<<4));
            half8 a1 = *(const half8*)(shb + (1+c)*16384 + ((512+(ks2<<6)+lane)<<4));
            half8 bw = *(const half8*)(wH + (((c<<3)+ks2)<<9) + (lane<<3));
            const int p = ks2&1;
            acm[0][p] = __builtin_amdgcn_mfma_f32_16x16x32_f16(a0,bw,acm[0][p],0,0,0);
            acm[1][p] = __builtin_amdgcn_mfma_f32_16x16x32_f16(a1,bw,acm[1][p],0,0,0);
          }
      }

      // ---- gates ----
      f32x4 A0 = acm[0][0] + acm[0][1];
      f32x4 A1 = acm[1][0] + acm[1][1];
      #pragma unroll
      for (int r = 0; r < 4; ++r) {
        glf[((((wv<<1)+0)<<4) + ((lane>>4)<<2)+r)*16 + (lane&15)] = A0[r];
        glf[((((wv<<1)+1)<<4) + ((lane>>4)<<2)+r)*16 + (lane&15)] = A1[r];
      }
      __syncthreads();
      {
        const int m  = erow >> 4;
        const int rr = erow & 15;
        float xi0 = glf[(((0*2+m)<<4)+rr)*16+ecol]   + bia[0];
        float xi1 = glf[(((0*2+m)<<4)+rr)*16+ecol+1] + bia[1];
        float xf0 = glf[(((1*2+m)<<4)+rr)*16+ecol]   + bia[2];
        float xf1 = glf[(((1*2+m)<<4)+rr)*16+ecol+1] + bia[3];
        float xg0 = glf[(((2*2+m)<<4)+rr)*16+ecol]   + bia[4];
        float xg1 = glf[(((2*2+m)<<4)+rr)*16+ecol+1] + bia[5];
        float xo0 = glf[(((3*2+m)<<4)+rr)*16+ecol]   + bia[6];
        float xo1 = glf[(((3*2+m)<<4)+rr)*16+ecol+1] + bia[7];
        float ii0 = 1.f/(1.f+__expf(-xi0));
        float ii1 = 1.f/(1.f+__expf(-xi1));
        float ff0 = 1.f/(1.f+__expf(-xf0));
        float ff1 = 1.f/(1.f+__expf(-xf1));
        float tg0 = 1.f - 2.f/(__expf(2.f*xg0)+1.f);
        float tg1 = 1.f - 2.f/(__expf(2.f*xg1)+1.f);
        float oo0 = 1.f/(1.f+__expf(-xo0));
        float oo1 = 1.f/(1.f+__expf(-xo1));
        c0 = ff0*c0 + ii0*tg0;
        c1 = ff1*c1 + ii1*tg1;
        float hv0 = oo0*(1.f - 2.f/(__expf(2.f*c0)+1.f));
        float hv1 = oo1*(1.f - 2.f/(__expf(2.f*c1)+1.f));
        union { h16 h[2]; uint32_t u; } pk;
        pk.h[0] = (h16)hv0; pk.h[1] = (h16)hv1;
        cstore4(h0r + (size_t)(t&(RING-1))*NB*NH + (size_t)(32*mh + erow)*NH + gcol0, pk.u);
      }
      VMW0();
      __syncthreads();
      if (tid == 0) AT_ST(&flags[fself], t+1);
    }
    return;  // layer0 done
  }

  // =================== LAYER 1 ===================
  {
    u32x4 st[16];
    // prologue: h0[0] ready after layer0 step 0 (fb0 >= 1); stage slot 0 -> chunks 0..3
    wgwaitP(flags + fb0, 1, flags + fb0, -1);
    {
      const h16* s0 = h0r + (size_t)0*NB*NH + (size_t)(32*mh)*NH;
      #pragma unroll
      for (int c = 0; c < 4; ++c)
        #pragma unroll
        for (int i = 0; i < 4; ++i)
          st[c*4+i] = cload16(s0 + (size_t)row_[i]*NH + (c<<8) + kl_[i]);
      VMW0();
      #pragma unroll
      for (int c = 0; c < 4; ++c) {
        *(u32x4*)(shb + c*16384 + ldsb_[0]) = st[c*4+0];
        *(u32x4*)(shb + c*16384 + ldsb_[1]) = st[c*4+1];
        *(u32x4*)(shb + c*16384 + ldsb_[2]) = st[c*4+2];
        *(u32x4*)(shb + c*16384 + ldsb_[3]) = st[c*4+3];
      }
      __syncthreads();
    }

    for (int s = 0; s < NT; ++s) {
      f32x4 acm[2][2] = {{{0.f,0.f,0.f,0.f},{0.f,0.f,0.f,0.f}},
                         {{0.f,0.f,0.f,0.f},{0.f,0.f,0.f,0.f}}};

      // ---- h0-sweep: chunks 0..3 hold h0[s] (staged in previous epilogue) ----
      {
        const h16* wA = w1p + ((size_t)((wv<<6)+cg) << 14);
        #pragma unroll
        for (int c = 0; c < 4; ++c)
          #pragma unroll
          for (int ks2 = 0; ks2 < 8; ++ks2) {
            half8 a0 = *(const half8*)(shb + c*16384 + (((ks2<<6)+lane)<<4));
            half8 a1 = *(const half8*)(shb + c*16384 + ((512+(ks2<<6)+lane)<<4));
            half8 bw = *(const half8*)(wA + (((c<<3)+ks2)<<9) + (lane<<3));
            const int p = ks2&1;
            acm[0][p] = __builtin_amdgcn_mfma_f32_16x16x32_f16(a0,bw,acm[0][p],0,0,0);
            acm[1][p] = __builtin_amdgcn_mfma_f32_16x16x32_f16(a1,bw,acm[1][p],0,0,0);
          }
      }

      // ---- wait own group (h1[s-1] ready), stage h1 -> chunks 4..7 ----
      wgwaitP(flags + fb1, s, flags + fb1, -1);
      {
        const h16* s1 = h1r + (size_t)((s+1)&1)*NB*NH + (size_t)(32*mh)*NH;
        #pragma unroll
        for (int c = 0; c < 4; ++c)
          #pragma unroll
          for (int i = 0; i < 4; ++i)
            st[c*4+i] = cload16(s1 + (size_t)row_[i]*NH + (c<<8) + kl_[i]);
        VMW0();
        #pragma unroll
        for (int c = 0; c < 4; ++c) {
          *(u32x4*)(shb + (4+c)*16384 + ldsb_[0]) = st[c*4+0];
          *(u32x4*)(shb + (4+c)*16384 + ldsb_[1]) = st[c*4+1];
          *(u32x4*)(shb + (4+c)*16384 + ldsb_[2]) = st[c*4+2];
          *(u32x4*)(shb + (4+c)*16384 + ldsb_[3]) = st[c*4+3];
        }
        __syncthreads();
      }

      // ---- h1-sweep (chunks 4..7) ----
      {
        const h16* wB = wh1p + ((size_t)((wv<<6)+cg) << 14);
        #pragma unroll
        for (int c = 0; c < 4; ++c)
          #pragma unroll
          for (int ks2 = 0; ks2 < 8; ++ks2) {
            half8 a0 = *(const half8*)(shb + (4+c)*16384 + (((ks2<<6)+lane)<<4));
            half8 a1 = *(const half8*)(shb + (4+c)*16384 + ((512+(ks2<<6)+lane)<<4));
            half8 bw = *(const half8*)(wB + (((c<<3)+ks2)<<9) + (lane<<3));
            const int p = ks2&1;
            acm[0][p] = __builtin_amdgcn_mfma_f32_16x16x32_f16(a0,bw,acm[0][p],0,0,0);
            acm[1][p] = __builtin_amdgcn_mfma_f32_16x16x32_f16(a1,bw,acm[1][p],0,0,0);
          }
      }

      // ---- gates ----
      f32x4 A0 = acm[0][0] + acm[0][1];
      f32x4 A1 = acm[1][0] + acm[1][1];
      #pragma unroll
      for (int r = 0; r < 4; ++r) {
        glf[((((wv<<1)+0)<<4) + ((lane>>4)<<2)+r)*16 + (lane&15)] = A0[r];
        glf[((((wv<<1)+1)<<4) + ((lane>>4)<<2)+r)*16 + (lane&15)] = A1[r];
      }
      __syncthreads();
      {
        const int m  = erow >> 4;
        const int rr = erow & 15;
        float xi0 = glf[(((0*2+m)<<4)+rr)*16+ecol]   + bia[0];
        float xi1 = glf[(((0*2+m)<<4)+rr)*16+ecol+1] + bia[1];
        float xf0 = glf[(((1*2+m)<<4)+rr)*16+ecol]   + bia[2];
        float xf1 = glf[(((1*2+m)<<4)+rr)*16+ecol+1] + bia[3];
        float xg0 = glf[(((2*2+m)<<4)+rr)*16+ecol]   + bia[4];
        float xg1 = glf[(((2*2+m)<<4)+rr)*16+ecol+1] + bia[5];
        float xo0 = glf[(((3*2+m)<<4)+rr)*16+ecol]   + bia[6];
        float xo1 = glf[(((3*2+m)<<4)+rr)*16+ecol+1] + bia[7];
        float ii0 = 1.f/(1.f+__expf(-xi0));
        float ii1 = 1.f/(1.f+__expf(-xi1));
        float ff0 = 1.f/(1.f+__expf(-xf0));
        float ff1 = 1.f/(1.f+__expf(-xf1));
        float tg0 = 1.f - 2.f/(__expf(2.f*xg0)+1.f);
        float tg1 = 1.f - 2.f/(__expf(2.f*xg1)+1.f);
        float oo0 = 1.f/(1.f+__expf(-xo0));
        float oo1 = 1.f/(1.f+__expf(-xo1));
        c0 = ff0*c0 + ii0*tg0;
        c1 = ff1*c1 + ii1*tg1;
        float hv0 = oo0*(1.f - 2.f/(__expf(2.f*c0)+1.f));
        float hv1 = oo1*(1.f - 2.f/(__expf(2.f*c1)+1.f));
        union { h16 h[2]; uint32_t u; } pk;
        pk.h[0] = (h16)hv0; pk.h[1] = (h16)hv1;
        cstore4(h1r + (size_t)(s&1)*NB*NH + (size_t)(32*mh + erow)*NH + gcol0, pk.u);
      }

      // ---- epilogue: stage h0[s+1] (slot (s+1)&63, needs fb0 >= s+2);
      //      drain h1-store + h0-loads together; then flag s+1 ----
      if (s + 1 < NT) {
        wgwaitP(flags + fb0, s + 2, flags + fb0, -1);   // normally instant
        const h16* s0 = h0r + (size_t)((s+1)&(RING-1))*NB*NH + (size_t)(32*mh)*NH;
        #pragma unroll
        for (int c = 0; c < 4; ++c)
          #pragma unroll
          for (int i = 0; i < 4; ++i)
            st[c*4+i] = cload16(s0 + (size_t)row_[i]*NH + (c<<8) + kl_[i]);
        VMW0();
        #pragma unroll
        for (int c = 0; c < 4; ++c) {
          *(u32x4*)(shb + c*16384 + ldsb_[0]) = st[c*4+0];
          *(u32x4*)(shb + c*16384 + ldsb_[1]) = st[c*4+1];
          *(u32x4*)(shb + c*16384 + ldsb_[2]) = st[c*4+2];
          *(u32x4*)(shb + c*16384 + ldsb_[3]) = st[c*4+3];
        }
        __syncthreads();
      } else {
        VMW0();
        __syncthreads();
      }
      if (tid == 0) AT_ST(&flags[fself], s+1);
    }
  }

  // ---- final FC: out[b] = h1[511][b,:] . wfc + bfc  (slot 1) ----
  if (wid != 128) return;
  wgwaitP(flags + 128, NT, flags + 192, NT);
  {
    const int b = tid >> 2, q = tid & 3;
    const unsigned long long* hp =
      (const unsigned long long*)(h1r + (size_t)NB*NH + (size_t)b*NH + (size_t)q*256);
    const float* wr = wfc + q*256;
    float sacc = 0.f;
    #pragma unroll 4
    for (int u = 0; u < 64; ++u) {
      unsigned long long v = AT_LD((unsigned long long*)(hp + u));
      h16 hh[4]; __builtin_memcpy(hh, &v, 8);
      sacc += (float)hh[0]*wr[4*u] + (float)hh[1]*wr[4*u+1]
            + (float)hh[2]*wr[4*u+2] + (float)hh[3]*wr[4*u+3];
    }
    glf[tid] = sacc;
    __syncthreads();
    if (tid < 64) {
      out[tid] = glf[4*tid] + glf[4*tid+1] + glf[4*tid+2] + glf[4*tid+3] + bfc[0];
    }
  }
}

extern "C" void kernel_launch(void* const* d_in, const int* in_sizes, int n_in,
                              void* d_out, int out_size, void* d_ws, size_t ws_size,
                              hipStream_t stream) {
  const float* x    = (const float*)d_in[0];
  const float* Wih0 = (const float*)d_in[1];
  const float* Whh0 = (const float*)d_in[2];
  const float* b0   = (const float*)d_in[3];
  const float* Wih1 = (const float*)d_in[4];
  const float* Whh1 = (const float*)d_in[5];
  const float* b1   = (const float*)d_in[6];
  const float* Wfc  = (const float*)d_in[7];
  const float* bfc  = (const float*)d_in[8];

  char* ws = (char*)d_ws;
  size_t off = 0;
  auto alloc = [&](size_t bytes)->void* {
    void* p = ws + off; off += (bytes + 255) & ~(size_t)255; return p;
  };
  h16* w0p  = (h16*)alloc((size_t)4096*ND*2);
  h16* wh0p = (h16*)alloc((size_t)4096*NH*2);
  h16* w1p  = (h16*)alloc((size_t)4096*NH*2);
  h16* wh1p = (h16*)alloc((size_t)4096*NH*2);
  h16* h0r  = (h16*)alloc((size_t)RING*NB*NH*2);
  h16* h1r  = (h16*)alloc((size_t)2*NB*NH*2);
  int* flags= (int*)alloc(256*sizeof(int));

  k_pack_w<<<(256*(ND/32)*64 + 255)/256, 256, 0, stream>>>(Wih0, w0p, ND);
  k_pack_w<<<(256*(NH/32)*64 + 255)/256, 256, 0, stream>>>(Whh0, wh0p, NH);
  k_pack_w<<<(256*(NH/32)*64 + 255)/256, 256, 0, stream>>>(Wih1, w1p, NH);
  k_pack_w<<<(256*(NH/32)*64 + 255)/256, 256, 0, stream>>>(Whh1, wh1p, NH);

  (void)hipFuncSetAttribute((const void*)k_lstm,
                            hipFuncAttributeMaxDynamicSharedMemorySize, 139264);
  k_lstm<<<256, 256, 139264, stream>>>(x, w0p, wh0p, w1p, wh1p,
                                       b0, b1, Wfc, bfc, h0r, h1r, flags,
                                       (float*)d_out);
}

// Round 6
// 4964.467 us; speedup vs baseline: 2.4260x; 1.2364x over previous
//
#include <hip/hip_runtime.h>
#include <hip/hip_fp16.h>
#include <stdint.h>

typedef _Float16 h16;
typedef h16  half8  __attribute__((ext_vector_type(8)));
typedef float f32x4 __attribute__((ext_vector_type(4)));
typedef uint32_t u32x4 __attribute__((ext_vector_type(4)));

#define NB 64
#define NT 512
#define ND 256
#define NH 1024
#define RING 64   // h0 ring depth (power of 2)

#define AT_LD(p)   __hip_atomic_load((p),      __ATOMIC_RELAXED, __HIP_MEMORY_SCOPE_AGENT)
#define AT_ST(p,v) __hip_atomic_store((p),(v), __ATOMIC_RELAXED, __HIP_MEMORY_SCOPE_AGENT)

// Coherent (L1/L2-bypass) 16B load / 4B store at the IF$ coherence point.
__device__ __forceinline__ u32x4 cload16(const void* p){
  u32x4 d;
  asm volatile("global_load_dwordx4 %0, %1, off sc0 sc1" : "=v"(d) : "v"(p) : "memory");
  return d;
}
__device__ __forceinline__ void cstore4(void* p, uint32_t v){
  asm volatile("global_store_dword %0, %1, off sc0 sc1" :: "v"(p), "v"(v) : "memory");
}
#define VMW0() asm volatile("s_waitcnt vmcnt(0)" ::: "memory")

// ---------------- prep: pack W [4096,K] fp32 -> fp16 MFMA-B-fragment order ----
__global__ void k_pack_w(const float* __restrict__ W, h16* __restrict__ P, int K){
  int tid = blockIdx.x*blockDim.x + threadIdx.x;
  int KS = K >> 5;
  int total = 256*KS*64;
  if (tid >= total) return;
  int l  = tid & 63;
  int ks = (tid >> 6) % KS;
  int nt = tid / (KS*64);
  const float* src = W + (size_t)(nt*16 + (l&15))*K + ks*32 + ((l>>4)<<3);
  float4 v0 = ((const float4*)src)[0];
  float4 v1 = ((const float4*)src)[1];
  half8 o;
  o[0]=(h16)v0.x; o[1]=(h16)v0.y; o[2]=(h16)v0.z; o[3]=(h16)v0.w;
  o[4]=(h16)v1.x; o[5]=(h16)v1.y; o[6]=(h16)v1.z; o[7]=(h16)v1.w;
  *(half8*)(P + (size_t)tid*8) = o;
}

// wave0 polls flags (lane l -> p0[l], optional p1[l]); others wait at barrier.
__device__ __forceinline__ void wgwaitP(const int* p0, int n0, const int* p1, int n1){
  if (threadIdx.x < 64) {
    int g = 0;
    for (;;) {
      bool ok = (AT_LD(p0 + threadIdx.x) >= n0);
      if (n1 >= 0) ok = ok && (AT_LD(p1 + threadIdx.x) >= n1);
      if (ok) break;
      __builtin_amdgcn_s_sleep(1);
      if (++g > (1<<22)) break;
    }
  }
  __syncthreads();
}

// ---------------- persistent decoupled 2-layer LSTM ----------------
// Round-4 protocol unchanged (proven). New: ALL weights register-resident
// (loaded once before the loop) -> zero L2 weight stream per step, removing
// ~1.5us/step of L2 BW plus the variance feeding the max-of-64 flag barrier.
__launch_bounds__(256, 1)
__global__ void k_lstm(const float* __restrict__ x,
                       const h16* __restrict__ w0p, const h16* __restrict__ wh0p,
                       const h16* __restrict__ w1p, const h16* __restrict__ wh1p,
                       const float* __restrict__ b0, const float* __restrict__ b1,
                       const float* __restrict__ wfc, const float* __restrict__ bfc,
                       h16* __restrict__ h0r, h16* __restrict__ h1r,
                       int* __restrict__ flags, float* __restrict__ out)
{
  extern __shared__ char shb[];                 // 8 chunks x 16KB A-panel, +8KB gates
  float* glf = (float*)(shb + 131072);

  const int tid   = threadIdx.x;
  const int lane  = tid & 63;
  const int wv    = tid >> 6;          // wave id == gate id (i,f,g,o)
  const int wid   = blockIdx.x;
  const int layer = wid >> 7;
  const int i2    = wid & 127;
  const int xcd   = i2 & 7;
  const int slot  = i2 >> 3;
  const int mh    = slot & 1;
  const int cg    = xcd*8 + (slot>>1); // 0..63

  const int erow  = tid >> 3;          // 0..31 local batch row
  const int ecol  = (tid & 7) << 1;
  const int gcol0 = cg*16 + ecol;

  const int fb0 = (mh<<6);             // f0 group base (this mh)
  const int fb1 = 128 + (mh<<6);       // f1 group base (this mh)
  const int fself = (layer ? fb1 : fb0) + cg;

  // per-thread staging geometry (iteration-invariant)
  int row_[4], kl_[4], ldsb_[4];
  #pragma unroll
  for (int i = 0; i < 4; ++i) {
    int sl = tid + (i<<8), m = sl>>9, rem = sl&511, ks = rem>>6, ln = rem&63;
    row_[i]  = (m<<4) + (ln&15);
    kl_[i]   = (ks<<5) + ((ln>>4)<<3);
    ldsb_[i] = ((((m<<3)+ks)<<6) + ln) << 4;
  }

  float bia[8];
  {
    const float* bb = layer ? b1 : b0;
    bia[0]=bb[0*NH+gcol0]; bia[1]=bb[0*NH+gcol0+1];
    bia[2]=bb[1*NH+gcol0]; bia[3]=bb[1*NH+gcol0+1];
    bia[4]=bb[2*NH+gcol0]; bia[5]=bb[2*NH+gcol0+1];
    bia[6]=bb[3*NH+gcol0]; bia[7]=bb[3*NH+gcol0+1];
  }
  float c0 = 0.f, c1 = 0.f;

  // ---- init: zero h0 ring slot RING-1 / h1 slot 1 (the t=-1 states), flag 0 ----
  {
    h16* z = layer ? (h1r + (size_t)1*NB*NH) : (h0r + (size_t)(RING-1)*NB*NH);
    cstore4(z + (size_t)(32*mh + erow)*NH + gcol0, 0u);
    VMW0();
    __syncthreads();
    if (tid == 0) AT_ST(&flags[fself], 0);
  }

  if (layer == 0) {
    // =================== LAYER 0 ===================
    // register-resident weights: Wih0 slice (8 frags) + Whh0 slice (32 frags)
    half8 wx[8], wh[32];
    {
      const h16* wX = w0p  + ((size_t)((wv<<6)+cg) << 12);
      #pragma unroll
      for (int i = 0; i < 8; ++i)  wx[i] = *(const half8*)(wX + (i<<9) + (lane<<3));
      const h16* wH = wh0p + ((size_t)((wv<<6)+cg) << 14);
      #pragma unroll
      for (int i = 0; i < 32; ++i) wh[i] = *(const half8*)(wH + (i<<9) + (lane<<3));
    }

    for (int t = 0; t < NT; ++t) {
      f32x4 acm[2][2] = {{{0.f,0.f,0.f,0.f},{0.f,0.f,0.f,0.f}},
                         {{0.f,0.f,0.f,0.f},{0.f,0.f,0.f,0.f}}};

      // ---- x stage (plain f32 loads + cvt) into LDS chunk 0 ----
      {
        const float* xr = x + ((size_t)(32*mh)*NT + t)*ND;
        #pragma unroll
        for (int i = 0; i < 4; ++i) {
          const float* p = xr + (size_t)row_[i]*(NT*ND) + kl_[i];
          float4 v0 = ((const float4*)p)[0];
          float4 v1 = ((const float4*)p)[1];
          half8 o;
          o[0]=(h16)v0.x; o[1]=(h16)v0.y; o[2]=(h16)v0.z; o[3]=(h16)v0.w;
          o[4]=(h16)v1.x; o[5]=(h16)v1.y; o[6]=(h16)v1.z; o[7]=(h16)v1.w;
          *(half8*)(shb + ldsb_[i]) = o;
        }
      }

      // ---- wait peers (h0[t-1] ready); ring guard vs layer1 when t>=64 ----
      wgwaitP(flags + fb0, t, flags + fb1, (t >= RING) ? (t - RING + 1) : -1);

      // ---- issue h0[t-1] coherent loads; x-sweep overlaps their flight ----
      u32x4 st[16];
      {
        const h16* s0 = h0r + (size_t)((t+RING-1)&(RING-1))*NB*NH + (size_t)(32*mh)*NH;
        #pragma unroll
        for (int c = 0; c < 4; ++c)
          #pragma unroll
          for (int i = 0; i < 4; ++i)
            st[c*4+i] = cload16(s0 + (size_t)row_[i]*NH + (c<<8) + kl_[i]);
      }
      #pragma unroll
      for (int ks2 = 0; ks2 < 8; ++ks2) {
        half8 a0 = *(const half8*)(shb + (((ks2<<6)+lane)<<4));
        half8 a1 = *(const half8*)(shb + ((512+(ks2<<6)+lane)<<4));
        const int p = ks2&1;
        acm[0][p] = __builtin_amdgcn_mfma_f32_16x16x32_f16(a0,wx[ks2],acm[0][p],0,0,0);
        acm[1][p] = __builtin_amdgcn_mfma_f32_16x16x32_f16(a1,wx[ks2],acm[1][p],0,0,0);
      }
      VMW0();
      #pragma unroll
      for (int c = 0; c < 4; ++c) {
        *(u32x4*)(shb + (1+c)*16384 + ldsb_[0]) = st[c*4+0];
        *(u32x4*)(shb + (1+c)*16384 + ldsb_[1]) = st[c*4+1];
        *(u32x4*)(shb + (1+c)*16384 + ldsb_[2]) = st[c*4+2];
        *(u32x4*)(shb + (1+c)*16384 + ldsb_[3]) = st[c*4+3];
      }
      __syncthreads();

      // ---- h-sweep (K=1024, B from regs) ----
      #pragma unroll
      for (int c = 0; c < 4; ++c)
        #pragma unroll
        for (int ks2 = 0; ks2 < 8; ++ks2) {
          half8 a0 = *(const half8*)(shb + (1+c)*16384 + (((ks2<<6)+lane)<<4));
          half8 a1 = *(const half8*)(shb + (1+c)*16384 + ((512+(ks2<<6)+lane)<<4));
          const int p = ks2&1;
          acm[0][p] = __builtin_amdgcn_mfma_f32_16x16x32_f16(a0,wh[(c<<3)+ks2],acm[0][p],0,0,0);
          acm[1][p] = __builtin_amdgcn_mfma_f32_16x16x32_f16(a1,wh[(c<<3)+ks2],acm[1][p],0,0,0);
        }

      // ---- gates ----
      f32x4 A0 = acm[0][0] + acm[0][1];
      f32x4 A1 = acm[1][0] + acm[1][1];
      #pragma unroll
      for (int r = 0; r < 4; ++r) {
        glf[((((wv<<1)+0)<<4) + ((lane>>4)<<2)+r)*16 + (lane&15)] = A0[r];
        glf[((((wv<<1)+1)<<4) + ((lane>>4)<<2)+r)*16 + (lane&15)] = A1[r];
      }
      __syncthreads();
      {
        const int m  = erow >> 4;
        const int rr = erow & 15;
        float xi0 = glf[(((0*2+m)<<4)+rr)*16+ecol]   + bia[0];
        float xi1 = glf[(((0*2+m)<<4)+rr)*16+ecol+1] + bia[1];
        float xf0 = glf[(((1*2+m)<<4)+rr)*16+ecol]   + bia[2];
        float xf1 = glf[(((1*2+m)<<4)+rr)*16+ecol+1] + bia[3];
        float xg0 = glf[(((2*2+m)<<4)+rr)*16+ecol]   + bia[4];
        float xg1 = glf[(((2*2+m)<<4)+rr)*16+ecol+1] + bia[5];
        float xo0 = glf[(((3*2+m)<<4)+rr)*16+ecol]   + bia[6];
        float xo1 = glf[(((3*2+m)<<4)+rr)*16+ecol+1] + bia[7];
        float ii0 = 1.f/(1.f+__expf(-xi0));
        float ii1 = 1.f/(1.f+__expf(-xi1));
        float ff0 = 1.f/(1.f+__expf(-xf0));
        float ff1 = 1.f/(1.f+__expf(-xf1));
        float tg0 = 1.f - 2.f/(__expf(2.f*xg0)+1.f);
        float tg1 = 1.f - 2.f/(__expf(2.f*xg1)+1.f);
        float oo0 = 1.f/(1.f+__expf(-xo0));
        float oo1 = 1.f/(1.f+__expf(-xo1));
        c0 = ff0*c0 + ii0*tg0;
        c1 = ff1*c1 + ii1*tg1;
        float hv0 = oo0*(1.f - 2.f/(__expf(2.f*c0)+1.f));
        float hv1 = oo1*(1.f - 2.f/(__expf(2.f*c1)+1.f));
        union { h16 h[2]; uint32_t u; } pk;
        pk.h[0] = (h16)hv0; pk.h[1] = (h16)hv1;
        cstore4(h0r + (size_t)(t&(RING-1))*NB*NH + (size_t)(32*mh + erow)*NH + gcol0, pk.u);
      }
      VMW0();
      __syncthreads();
      if (tid == 0) AT_ST(&flags[fself], t+1);
    }
    return;  // layer0 done
  }

  // =================== LAYER 1 ===================
  {
    // register-resident weights: Wih1 slice (32 frags) + Whh1 slice (32 frags)
    half8 wa[32], wb2[32];
    {
      const h16* wA = w1p  + ((size_t)((wv<<6)+cg) << 14);
      #pragma unroll
      for (int i = 0; i < 32; ++i) wa[i]  = *(const half8*)(wA + (i<<9) + (lane<<3));
      const h16* wB = wh1p + ((size_t)((wv<<6)+cg) << 14);
      #pragma unroll
      for (int i = 0; i < 32; ++i) wb2[i] = *(const half8*)(wB + (i<<9) + (lane<<3));
    }

    u32x4 st[16];
    // prologue: h0[0] ready after layer0 step 0 (fb0 >= 1); stage slot 0 -> chunks 0..3
    wgwaitP(flags + fb0, 1, flags + fb0, -1);
    {
      const h16* s0 = h0r + (size_t)0*NB*NH + (size_t)(32*mh)*NH;
      #pragma unroll
      for (int c = 0; c < 4; ++c)
        #pragma unroll
        for (int i = 0; i < 4; ++i)
          st[c*4+i] = cload16(s0 + (size_t)row_[i]*NH + (c<<8) + kl_[i]);
      VMW0();
      #pragma unroll
      for (int c = 0; c < 4; ++c) {
        *(u32x4*)(shb + c*16384 + ldsb_[0]) = st[c*4+0];
        *(u32x4*)(shb + c*16384 + ldsb_[1]) = st[c*4+1];
        *(u32x4*)(shb + c*16384 + ldsb_[2]) = st[c*4+2];
        *(u32x4*)(shb + c*16384 + ldsb_[3]) = st[c*4+3];
      }
      __syncthreads();
    }

    for (int s = 0; s < NT; ++s) {
      f32x4 acm[2][2] = {{{0.f,0.f,0.f,0.f},{0.f,0.f,0.f,0.f}},
                         {{0.f,0.f,0.f,0.f},{0.f,0.f,0.f,0.f}}};

      // ---- h0-sweep: chunks 0..3 hold h0[s]; B from regs ----
      #pragma unroll
      for (int c = 0; c < 4; ++c)
        #pragma unroll
        for (int ks2 = 0; ks2 < 8; ++ks2) {
          half8 a0 = *(const half8*)(shb + c*16384 + (((ks2<<6)+lane)<<4));
          half8 a1 = *(const half8*)(shb + c*16384 + ((512+(ks2<<6)+lane)<<4));
          const int p = ks2&1;
          acm[0][p] = __builtin_amdgcn_mfma_f32_16x16x32_f16(a0,wa[(c<<3)+ks2],acm[0][p],0,0,0);
          acm[1][p] = __builtin_amdgcn_mfma_f32_16x16x32_f16(a1,wa[(c<<3)+ks2],acm[1][p],0,0,0);
        }

      // ---- wait own group (h1[s-1] ready), stage h1 -> chunks 4..7 ----
      wgwaitP(flags + fb1, s, flags + fb1, -1);
      {
        const h16* s1 = h1r + (size_t)((s+1)&1)*NB*NH + (size_t)(32*mh)*NH;
        #pragma unroll
        for (int c = 0; c < 4; ++c)
          #pragma unroll
          for (int i = 0; i < 4; ++i)
            st[c*4+i] = cload16(s1 + (size_t)row_[i]*NH + (c<<8) + kl_[i]);
        VMW0();
        #pragma unroll
        for (int c = 0; c < 4; ++c) {
          *(u32x4*)(shb + (4+c)*16384 + ldsb_[0]) = st[c*4+0];
          *(u32x4*)(shb + (4+c)*16384 + ldsb_[1]) = st[c*4+1];
          *(u32x4*)(shb + (4+c)*16384 + ldsb_[2]) = st[c*4+2];
          *(u32x4*)(shb + (4+c)*16384 + ldsb_[3]) = st[c*4+3];
        }
        __syncthreads();
      }

      // ---- h1-sweep (chunks 4..7, B from regs) ----
      #pragma unroll
      for (int c = 0; c < 4; ++c)
        #pragma unroll
        for (int ks2 = 0; ks2 < 8; ++ks2) {
          half8 a0 = *(const half8*)(shb + (4+c)*16384 + (((ks2<<6)+lane)<<4));
          half8 a1 = *(const half8*)(shb + (4+c)*16384 + ((512+(ks2<<6)+lane)<<4));
          const int p = ks2&1;
          acm[0][p] = __builtin_amdgcn_mfma_f32_16x16x32_f16(a0,wb2[(c<<3)+ks2],acm[0][p],0,0,0);
          acm[1][p] = __builtin_amdgcn_mfma_f32_16x16x32_f16(a1,wb2[(c<<3)+ks2],acm[1][p],0,0,0);
        }

      // ---- gates ----
      f32x4 A0 = acm[0][0] + acm[0][1];
      f32x4 A1 = acm[1][0] + acm[1][1];
      #pragma unroll
      for (int r = 0; r < 4; ++r) {
        glf[((((wv<<1)+0)<<4) + ((lane>>4)<<2)+r)*16 + (lane&15)] = A0[r];
        glf[((((wv<<1)+1)<<4) + ((lane>>4)<<2)+r)*16 + (lane&15)] = A1[r];
      }
      __syncthreads();
      {
        const int m  = erow >> 4;
        const int rr = erow & 15;
        float xi0 = glf[(((0*2+m)<<4)+rr)*16+ecol]   + bia[0];
        float xi1 = glf[(((0*2+m)<<4)+rr)*16+ecol+1] + bia[1];
        float xf0 = glf[(((1*2+m)<<4)+rr)*16+ecol]   + bia[2];
        float xf1 = glf[(((1*2+m)<<4)+rr)*16+ecol+1] + bia[3];
        float xg0 = glf[(((2*2+m)<<4)+rr)*16+ecol]   + bia[4];
        float xg1 = glf[(((2*2+m)<<4)+rr)*16+ecol+1] + bia[5];
        float xo0 = glf[(((3*2+m)<<4)+rr)*16+ecol]   + bia[6];
        float xo1 = glf[(((3*2+m)<<4)+rr)*16+ecol+1] + bia[7];
        float ii0 = 1.f/(1.f+__expf(-xi0));
        float ii1 = 1.f/(1.f+__expf(-xi1));
        float ff0 = 1.f/(1.f+__expf(-xf0));
        float ff1 = 1.f/(1.f+__expf(-xf1));
        float tg0 = 1.f - 2.f/(__expf(2.f*xg0)+1.f);
        float tg1 = 1.f - 2.f/(__expf(2.f*xg1)+1.f);
        float oo0 = 1.f/(1.f+__expf(-xo0));
        float oo1 = 1.f/(1.f+__expf(-xo1));
        c0 = ff0*c0 + ii0*tg0;
        c1 = ff1*c1 + ii1*tg1;
        float hv0 = oo0*(1.f - 2.f/(__expf(2.f*c0)+1.f));
        float hv1 = oo1*(1.f - 2.f/(__expf(2.f*c1)+1.f));
        union { h16 h[2]; uint32_t u; } pk;
        pk.h[0] = (h16)hv0; pk.h[1] = (h16)hv1;
        cstore4(h1r + (size_t)(s&1)*NB*NH + (size_t)(32*mh + erow)*NH + gcol0, pk.u);
      }

      // ---- epilogue: stage h0[s+1] (slot (s+1)&63, needs fb0 >= s+2);
      //      drain h1-store + h0-loads together; then flag s+1 ----
      if (s + 1 < NT) {
        wgwaitP(flags + fb0, s + 2, flags + fb0, -1);   // normally instant
        const h16* s0 = h0r + (size_t)((s+1)&(RING-1))*NB*NH + (size_t)(32*mh)*NH;
        #pragma unroll
        for (int c = 0; c < 4; ++c)
          #pragma unroll
          for (int i = 0; i < 4; ++i)
            st[c*4+i] = cload16(s0 + (size_t)row_[i]*NH + (c<<8) + kl_[i]);
        VMW0();
        #pragma unroll
        for (int c = 0; c < 4; ++c) {
          *(u32x4*)(shb + c*16384 + ldsb_[0]) = st[c*4+0];
          *(u32x4*)(shb + c*16384 + ldsb_[1]) = st[c*4+1];
          *(u32x4*)(shb + c*16384 + ldsb_[2]) = st[c*4+2];
          *(u32x4*)(shb + c*16384 + ldsb_[3]) = st[c*4+3];
        }
        __syncthreads();
      } else {
        VMW0();
        __syncthreads();
      }
      if (tid == 0) AT_ST(&flags[fself], s+1);
    }
  }

  // ---- final FC: out[b] = h1[511][b,:] . wfc + bfc  (slot 1) ----
  if (wid != 128) return;
  wgwaitP(flags + 128, NT, flags + 192, NT);
  {
    const int b = tid >> 2, q = tid & 3;
    const unsigned long long* hp =
      (const unsigned long long*)(h1r + (size_t)NB*NH + (size_t)b*NH + (size_t)q*256);
    const float* wr = wfc + q*256;
    float sacc = 0.f;
    #pragma unroll 4
    for (int u = 0; u < 64; ++u) {
      unsigned long long v = AT_LD((unsigned long long*)(hp + u));
      h16 hh[4]; __builtin_memcpy(hh, &v, 8);
      sacc += (float)hh[0]*wr[4*u] + (float)hh[1]*wr[4*u+1]
            + (float)hh[2]*wr[4*u+2] + (float)hh[3]*wr[4*u+3];
    }
    glf[tid] = sacc;
    __syncthreads();
    if (tid < 64) {
      out[tid] = glf[4*tid] + glf[4*tid+1] + glf[4*tid+2] + glf[4*tid+3] + bfc[0];
    }
  }
}

extern "C" void kernel_launch(void* const* d_in, const int* in_sizes, int n_in,
                              void* d_out, int out_size, void* d_ws, size_t ws_size,
                              hipStream_t stream) {
  const float* x    = (const float*)d_in[0];
  const float* Wih0 = (const float*)d_in[1];
  const float* Whh0 = (const float*)d_in[2];
  const float* b0   = (const float*)d_in[3];
  const float* Wih1 = (const float*)d_in[4];
  const float* Whh1 = (const float*)d_in[5];
  const float* b1   = (const float*)d_in[6];
  const float* Wfc  = (const float*)d_in[7];
  const float* bfc  = (const float*)d_in[8];

  char* ws = (char*)d_ws;
  size_t off = 0;
  auto alloc = [&](size_t bytes)->void* {
    void* p = ws + off; off += (bytes + 255) & ~(size_t)255; return p;
  };
  h16* w0p  = (h16*)alloc((size_t)4096*ND*2);
  h16* wh0p = (h16*)alloc((size_t)4096*NH*2);
  h16* w1p  = (h16*)alloc((size_t)4096*NH*2);
  h16* wh1p = (h16*)alloc((size_t)4096*NH*2);
  h16* h0r  = (h16*)alloc((size_t)RING*NB*NH*2);
  h16* h1r  = (h16*)alloc((size_t)2*NB*NH*2);
  int* flags= (int*)alloc(256*sizeof(int));

  k_pack_w<<<(256*(ND/32)*64 + 255)/256, 256, 0, stream>>>(Wih0, w0p, ND);
  k_pack_w<<<(256*(NH/32)*64 + 255)/256, 256, 0, stream>>>(Whh0, wh0p, NH);
  k_pack_w<<<(256*(NH/32)*64 + 255)/256, 256, 0, stream>>>(Wih1, w1p, NH);
  k_pack_w<<<(256*(NH/32)*64 + 255)/256, 256, 0, stream>>>(Whh1, wh1p, NH);

  (void)hipFuncSetAttribute((const void*)k_lstm,
                            hipFuncAttributeMaxDynamicSharedMemorySize, 139264);
  k_lstm<<<256, 256, 139264, stream>>>(x, w0p, wh0p, w1p, wh1p,
                                       b0, b1, Wfc, bfc, h0r, h1r, flags,
                                       (float*)d_out);
}